// Round 1
// baseline (20201.875 us; speedup 1.0000x reference)
//
#include <hip/hip_runtime.h>
#include <hip/hip_bf16.h>

// bigRSNN: T=8192 sequential spiking RNN. Phase 1: 64 persistent-ish blocks,
// each owns 16 neurons (V rows in VGPRs), exchanging 16-bit spike words per
// step through tag-stamped agent-scope u32s in ws. Phase 2: readout GEMM over
// the recorded spike raster + 10 scalar IIR scans + head mean.

constexpr int T_STEPS = 8192;
constexpr int IN_DIM  = 192;
constexpr int H_DIM   = 1024;
constexpr int NBLK    = 64;   // spike-word producers, 16 rows each

// ---------------------------------------------------------------- clear ws
__global__ void k_clear(unsigned int* __restrict__ p, int n) {
    int i = blockIdx.x * blockDim.x + threadIdx.x;
    if (i < n) p[i] = 0u;
}

// ---------------------------------------------------------------- phase 1
// grid 64 x 512. tid = r_local*32 + cg. Thread holds V[row][cg*32..+31] (8
// float4) and W_in[row][cg*6..+5] in registers. wave0 polls remote spike
// words; wave1 double-buffers x[t] into LDS one step ahead.
__global__ __launch_bounds__(512, 1) void k_phase1(
    const float* __restrict__ x,       // [T][192]
    const float* __restrict__ W_in,    // [H][192]
    const float* __restrict__ V,       // [H][H]
    const float* __restrict__ b_rec,   // [H]
    const float* __restrict__ alpha_h_p,
    const float* __restrict__ beta_h_p,
    unsigned int* __restrict__ spkWords) // [T][64] : (t+1)<<16 | bits16
{
    const int tid     = threadIdx.x;
    const int blk     = blockIdx.x;        // 0..63
    const int r_local = tid >> 5;          // 0..15
    const int cg      = tid & 31;          // 0..31
    const int row     = (blk << 4) + r_local;
    const int wave    = tid >> 6;          // 0..7
    const int wl      = tid & 63;

    __shared__ unsigned int lds_bits[64];
    __shared__ unsigned int lds_sp[16];
    __shared__ float        x_lds[2][IN_DIM];

    // V fragment: 32 consecutive columns, 8x float4 in VGPRs
    float4 vfrag[8];
    {
        const float4* vp = (const float4*)(V + (size_t)row * H_DIM + cg * 32);
        #pragma unroll
        for (int i = 0; i < 8; ++i) vfrag[i] = vp[i];
    }
    // W_in fragment: 6 consecutive k
    float wfrag[6];
    {
        const float* wp = W_in + row * IN_DIM + cg * 6;
        #pragma unroll
        for (int i = 0; i < 6; ++i) wfrag[i] = wp[i];
    }
    const float b_r = b_rec[row];
    const float ah  = alpha_h_p[0];
    const float bh  = beta_h_p[0];

    if (tid < IN_DIM) x_lds[0][tid] = 0.0f;   // x[-1] = 0 (slot 0, step 0)

    float4 vx = make_float4(0.f, 0.f, 0.f, 0.f);
    if (wave == 1 && wl < 48)                  // preload x[0] (48 float4 = 192 f)
        vx = *(const float4*)(x + (wl << 2));

    float syn = 0.f, mem = 0.f, prev = 0.f;    // replicated across the 32 lanes of a row
    __syncthreads();

    for (int t = 0; t < T_STEPS; ++t) {
        // ---- pre-barrier-A: wave0 gathers S_{t-1} words into LDS ----
        if (wave == 0) {
            unsigned int wb = 0u;
            if (t > 0) {
                const unsigned int want = (unsigned int)t;  // producer wrote tag t at step t-1
                unsigned int vv;
                do {
                    vv = __hip_atomic_load(&spkWords[(size_t)(t - 1) * 64 + wl],
                                           __ATOMIC_RELAXED, __HIP_MEMORY_SCOPE_AGENT);
                } while (__ballot((vv >> 16) != want));
                wb = vv & 0xffffu;
            }
            lds_bits[wl] = wb;
        }
        asm volatile("s_waitcnt vmcnt(0) lgkmcnt(0)" ::: "memory");
        __builtin_amdgcn_s_barrier();          // A: bits published, x slot ready
        __builtin_amdgcn_sched_barrier(0);

        // ---- wave1: write x[t] (in regs) into slot (t+1)&1, fetch x[t+1] ----
        if (wave == 1 && wl < 48) {
            *(float4*)&x_lds[(t + 1) & 1][wl << 2] = vx;
            int nt = (t + 1 < T_STEPS) ? (t + 1) : (T_STEPS - 1);
            vx = *(const float4*)(x + (size_t)nt * IN_DIM + (wl << 2));
        }

        // ---- V @ S_{t-1} over my 32 columns ----
        unsigned int w0 = lds_bits[cg << 1];
        unsigned int w1 = lds_bits[(cg << 1) + 1];
        unsigned int bits = (w0 & 0xffffu) | (w1 << 16);

        float acc = 0.f;
        #pragma unroll
        for (int i = 0; i < 8; ++i) {
            acc = fmaf((float)((bits >> (4 * i + 0)) & 1u), vfrag[i].x, acc);
            acc = fmaf((float)((bits >> (4 * i + 1)) & 1u), vfrag[i].y, acc);
            acc = fmaf((float)((bits >> (4 * i + 2)) & 1u), vfrag[i].z, acc);
            acc = fmaf((float)((bits >> (4 * i + 3)) & 1u), vfrag[i].w, acc);
        }
        // ---- + W_in @ x[t-1] over my 6 k's ----
        const float* xs = &x_lds[t & 1][cg * 6];
        #pragma unroll
        for (int i = 0; i < 6; ++i) acc = fmaf(wfrag[i], xs[i], acc);

        // ---- reduce across the 32 lanes of this row ----
        #pragma unroll
        for (int m = 1; m < 32; m <<= 1) acc += __shfl_xor(acc, m, 64);

        // ---- state update (identical in all 32 lanes of the row) ----
        float cur = acc + b_r;
        syn = fmaf(ah, syn, cur);
        mem = fmaf(bh, mem, syn) * (1.0f - prev);   // zero-reset w/ previous spike
        float spk = (mem > 1.0f) ? 1.0f : 0.0f;
        prev = spk;
        if (cg == 0) lds_sp[r_local] = (spk > 0.5f) ? (1u << r_local) : 0u;

        asm volatile("s_waitcnt lgkmcnt(0)" ::: "memory");
        __builtin_amdgcn_s_barrier();          // B: spike bits in LDS
        __builtin_amdgcn_sched_barrier(0);

        if (tid == 0) {
            unsigned int all = 0u;
            #pragma unroll
            for (int i = 0; i < 16; ++i) all |= lds_sp[i];
            __hip_atomic_store(&spkWords[(size_t)t * 64 + blk],
                               ((unsigned int)(t + 1) << 16) | all,
                               __ATOMIC_RELAXED, __HIP_MEMORY_SCOPE_AGENT);
        }
    }
}

// ---------------------------------------------------------------- phase 2A
// R[t][row] = W_out[row] . S_{t-1}  (row = h*2+o, 10 rows). W_out staged in
// LDS with +9 pad (stride 1033) to break the 10-way row-bank conflict.
__global__ __launch_bounds__(256, 1) void k_readout_mm(
    const unsigned int* __restrict__ spkWords,
    const float* __restrict__ W_out,   // [10][1024]
    float* __restrict__ R)             // [T][10]
{
    __shared__ float wlds[10 * 1033];
    for (int i = threadIdx.x; i < 10 * 1024; i += 256) {
        int r = i >> 10, c = i & 1023;
        wlds[r * 1033 + c] = W_out[i];
    }
    __syncthreads();

    int tid = threadIdx.x;
    if (tid >= 250) return;
    int tl = tid / 10, rowr = tid - tl * 10;
    int t = blockIdx.x * 25 + tl;
    if (t >= T_STEPS) return;

    float acc = 0.f;
    if (t > 0) {
        const unsigned int* wp = spkWords + (size_t)(t - 1) * 64;
        const float* wr = &wlds[rowr * 1033];
        for (int w = 0; w < 64; ++w) {
            unsigned int bits = wp[w] & 0xffffu;
            const float* wb = wr + w * 16;
            #pragma unroll
            for (int j = 0; j < 16; ++j)
                acc = fmaf((float)((bits >> j) & 1u), wb[j], acc);
        }
    }
    R[t * 10 + rowr] = acc;
}

// ---------------------------------------------------------------- phase 2B
// 10 independent 2-stage IIRs over T, lane = row = h*2+o. Software-pipelined
// loads (depth 8, fully unrolled so buf[] stays in registers).
__global__ void k_scan(const float* __restrict__ R,
                       const float* __restrict__ alpha_r,
                       const float* __restrict__ beta_r,
                       float* __restrict__ memr_all)   // [T][10]
{
    int lane = threadIdx.x;
    bool act = lane < 10;
    float a = act ? alpha_r[lane >> 1] : 0.f;
    float b = act ? beta_r[lane >> 1] : 0.f;
    float syn = 0.f, mem = 0.f;
    constexpr int PF = 8;
    float buf[PF];
    #pragma unroll
    for (int i = 0; i < PF; ++i) buf[i] = act ? R[i * 10 + lane] : 0.f;

    for (int tb = 0; tb < T_STEPS; tb += PF) {
        #pragma unroll
        for (int i = 0; i < PF; ++i) {
            int t = tb + i;
            syn = fmaf(a, syn, buf[i]);
            mem = fmaf(b, mem, syn);
            if (act) memr_all[t * 10 + lane] = mem;
            int tn = t + PF;
            buf[i] = (act && tn < T_STEPS) ? R[tn * 10 + lane] : 0.f;
        }
    }
}

// ---------------------------------------------------------------- phase 2C
__global__ void k_mean(const float* __restrict__ memr_all, float* __restrict__ out) {
    int g = blockIdx.x * blockDim.x + threadIdx.x;
    if (g >= T_STEPS * 2) return;
    int t = g >> 1, o = g & 1;
    const float* m = memr_all + t * 10 + o;
    out[g] = 0.2f * (m[0] + m[2] + m[4] + m[6] + m[8]);
}

// ---------------------------------------------------------------- launch
extern "C" void kernel_launch(void* const* d_in, const int* in_sizes, int n_in,
                              void* d_out, int out_size, void* d_ws, size_t ws_size,
                              hipStream_t stream) {
    (void)in_sizes; (void)n_in; (void)out_size; (void)ws_size;
    const float* x       = (const float*)d_in[0];
    const float* W_in    = (const float*)d_in[1];
    const float* V       = (const float*)d_in[2];
    const float* b_rec   = (const float*)d_in[3];
    const float* W_out   = (const float*)d_in[4];
    const float* alpha_h = (const float*)d_in[5];
    const float* beta_h  = (const float*)d_in[6];
    const float* alpha_r = (const float*)d_in[7];
    const float* beta_r  = (const float*)d_in[8];
    float* out = (float*)d_out;

    unsigned int* spkWords = (unsigned int*)d_ws;                           // 2 MB
    float* R        = (float*)((char*)d_ws + (size_t)T_STEPS * 64 * 4);     // 320 KB
    float* memr_all = R + (size_t)T_STEPS * 10;                             // 320 KB

    int nclr = T_STEPS * 64;
    k_clear<<<(nclr + 255) / 256, 256, 0, stream>>>(spkWords, nclr);
    k_phase1<<<NBLK, 512, 0, stream>>>(x, W_in, V, b_rec, alpha_h, beta_h, spkWords);
    k_readout_mm<<<(T_STEPS + 24) / 25, 256, 0, stream>>>(spkWords, W_out, R);
    k_scan<<<1, 64, 0, stream>>>(R, alpha_r, beta_r, memr_all);
    k_mean<<<(T_STEPS * 2 + 255) / 256, 256, 0, stream>>>(memr_all, out);
}